// Round 3
// baseline (1565.549 us; speedup 1.0000x reference)
//
#include <hip/hip_runtime.h>
#include <math.h>

// M=2048, AVGF=16 (17 rows), HA=16 heads, DH=128, TK=4 blocks.
// GEMM: out[i,l] = sum_m act'[i,m] * W[l,m]; k-split partials P[y][i][l],
// plain stores, then reduce kernels (no global atomics except tiny LN stats).

// ---------------- init: ss=bias(+cls), altx, zero st0/st1, row-0 stats ----
__global__ void k0_init(const float* __restrict__ x,
                        const float* __restrict__ bias,
                        const float* __restrict__ cls,
                        float* __restrict__ ss,
                        float* __restrict__ altx,
                        float* __restrict__ st01) {
    int idx = blockIdx.x * 256 + threadIdx.x;
    if (idx < 17 * 2048) {
        int r = idx >> 11, m = idx & 2047;
        float v = bias[idx];
        if (r == 0) v += cls[m];
        ss[idx] = v;
    }
    if (idx < 16 * 2048) {
        int i = idx >> 11, m = idx & 2047;
        int c1 = m >> 6, c2 = m & 63;
        const float* p = x + (size_t)(c2 * 32 + c1) * 160 + i * 10;
        float s = 0.f;
#pragma unroll
        for (int j = 0; j < 10; ++j) s += p[j];
        altx[idx] = s * 0.1f;
    }
    if (blockIdx.x == 0) {
        int t = threadIdx.x;
        if (t < 68) st01[t] = 0.f;
        __syncthreads();
        float s = 0.f, q = 0.f;
        for (int j = t; j < 2048; j += 256) {
            float v = bias[j] + cls[j];
            s += v; q += v * v;
        }
#pragma unroll
        for (int off = 32; off; off >>= 1) {
            s += __shfl_xor(s, off);
            q += __shfl_xor(q, off);
        }
        __shared__ float ls[4], lq[4];
        int w = t >> 6;
        if ((t & 63) == 0) { ls[w] = s; lq[w] = q; }
        __syncthreads();
        if (t == 0) {
            st01[0] = ls[0] + ls[1] + ls[2] + ls[3];
            st01[1] = lq[0] + lq[1] + lq[2] + lq[3];
        }
    }
}

// ---------------- skinny GEMM, partial output ----------------------------
// block: 256 thr = 4 waves; covers 256 output cols l = l0 + lane + 64q.
// wave w handles m-slice [w*8, w*8+8) of each 32-wide k-tile; KT tiles/block.
// MODE 0: act' = act ; MODE 1: act' = LN(act) from raw (sum,sumsq) in st.
template <int NR, int MODE, int KT>
__global__ __launch_bounds__(256) void gemm2(
    const float* __restrict__ W, const float* __restrict__ act,
    const float* __restrict__ st, const float* __restrict__ g,
    const float* __restrict__ b, float* __restrict__ P,
    float* __restrict__ zst, int L, int K) {
    __shared__ float Wl[256 * 36];   // padded [l][36]; aliased as R[NR][256] at end
    __shared__ float al[NR][32];
    int tid = threadIdx.x;
    int lane = tid & 63, wv = tid >> 6;
    int l0 = blockIdx.x * 256;
    if (zst != nullptr && blockIdx.x == 0 && blockIdx.y == 0 && tid < 34)
        zst[tid] = 0.f;
    float acc[NR][4];
#pragma unroll
    for (int i = 0; i < NR; ++i)
#pragma unroll
        for (int q = 0; q < 4; ++q) acc[i][q] = 0.f;
    int c4 = tid & 7, rw = tid >> 3;
    int kbase = blockIdx.y * (KT * 32);
    for (int t = 0; t < KT; ++t) {
        int kt = kbase + t * 32;
        for (int e = tid; e < NR * 32; e += 256) {
            int i = e >> 5, ml = e & 31;
            float v = act[(size_t)i * K + kt + ml];
            if (MODE == 1) {
                float mean = st[2 * i] * (1.f / 2048.f);
                float var = st[2 * i + 1] * (1.f / 2048.f) - mean * mean;
                float rstd = rsqrtf(var + 1e-5f);
                int m = kt + ml;
                v = (v - mean) * rstd * g[m] + b[m];
            }
            al[i][ml] = v;
        }
#pragma unroll
        for (int r8 = 0; r8 < 8; ++r8) {
            int rr = r8 * 32 + rw;
            const float4 w4 = *reinterpret_cast<const float4*>(
                W + (size_t)(l0 + rr) * K + kt + c4 * 4);
            *reinterpret_cast<float4*>(&Wl[rr * 36 + c4 * 4]) = w4;
        }
        __syncthreads();
        int w8 = wv * 8;
#pragma unroll
        for (int h = 0; h < 2; ++h) {
            int mm = w8 + h * 4;
            float4 wv4[4];
#pragma unroll
            for (int q = 0; q < 4; ++q)
                wv4[q] = *reinterpret_cast<const float4*>(&Wl[(lane + 64 * q) * 36 + mm]);
#pragma unroll
            for (int i = 0; i < NR; ++i) {
                const float4 a4 = *reinterpret_cast<const float4*>(&al[i][mm]);
#pragma unroll
                for (int q = 0; q < 4; ++q)
                    acc[i][q] += a4.x * wv4[q].x + a4.y * wv4[q].y +
                                 a4.z * wv4[q].z + a4.w * wv4[q].w;
            }
        }
        __syncthreads();
    }
    // cross-wave k-reduction in LDS (alias Wl), then coalesced partial store
    float* R = Wl;
    for (int e = tid; e < NR * 256; e += 256) R[e] = 0.f;
    __syncthreads();
#pragma unroll
    for (int i = 0; i < NR; ++i)
#pragma unroll
        for (int q = 0; q < 4; ++q)
            atomicAdd(&R[i * 256 + lane + 64 * q], acc[i][q]);
    __syncthreads();
    size_t pb = (size_t)blockIdx.y * NR * L + l0 + tid;
#pragma unroll
    for (int i = 0; i < NR; ++i)
        P[pb + (size_t)i * L] = R[i * 256 + tid];
}

// ---------------- reduces ------------------------------------------------
__global__ void red_plain(const float* __restrict__ P, float* __restrict__ out,
                          int S, int NRL) {
    int idx = blockIdx.x * 256 + threadIdx.x;
    float s = 0.f;
    for (int y = 0; y < S; ++y) s += P[(size_t)y * NRL + idx];
    out[idx] = s;
}

__global__ void red_gelu(const float* __restrict__ P, const float* __restrict__ fb,
                         float* __restrict__ out, int S, int NRL, int Lm) {
    int idx = blockIdx.x * 256 + threadIdx.x;
    float s = fb[idx & Lm];
    for (int y = 0; y < S; ++y) s += P[(size_t)y * NRL + idx];
    out[idx] = 0.5f * s * (1.f + erff(s * 0.70710678f));
}

// ss[idx] += sum(+bias); accumulate new-row (sum,sumsq) into st (pre-zeroed)
__global__ void red_addss(const float* __restrict__ P, const float* __restrict__ fb,
                          float* __restrict__ ss, float* __restrict__ st,
                          int S, int NRL) {
    int idx = blockIdx.x * 256 + threadIdx.x;
    float s = (fb != nullptr) ? fb[idx & 2047] : 0.f;
    for (int y = 0; y < S; ++y) s += P[(size_t)y * NRL + idx];
    float v = ss[idx] + s;
    ss[idx] = v;
    float sv = v, q = v * v;
#pragma unroll
    for (int off = 32; off; off >>= 1) {
        sv += __shfl_xor(sv, off);
        q += __shfl_xor(q, off);
    }
    if ((threadIdx.x & 63) == 0) {
        int i = idx >> 11;
        atomicAdd(&st[2 * i], sv);
        atomicAdd(&st[2 * i + 1], q);
    }
}

// ---------------- attention (+ zero st1 for this iter) -------------------
__global__ void attn_kernel(const float* __restrict__ qkv, float* __restrict__ imv,
                            float* __restrict__ st1) {
    int h = blockIdx.x, lane = threadIdx.x;
    if (h == 0 && lane < 34) st1[lane] = 0.f;
    const float scale = 0.08838834764831845f;  // 1/sqrt(128)
    float run0 = 0.f, run1 = 0.f;
    for (int i = 0; i < 17; ++i) {
        const float* base = qkv + (size_t)i * 6144 + h * 128;
        float q0 = base[lane], q1 = base[lane + 64];
        float k0 = base[2048 + lane], k1 = base[2048 + lane + 64];
        float v0 = base[4096 + lane], v1 = base[4096 + lane + 64];
        float p = q0 * k0 + q1 * k1;
#pragma unroll
        for (int off = 32; off; off >>= 1) p += __shfl_xor(p, off);
        float rsa = p * scale;
        float iv0 = rsa * v0, iv1 = rsa * v1;
        float o0, o1;
        if (i < 16) { run0 += iv0; run1 += iv1; o0 = run0; o1 = run1; }
        else        { o0 = iv0; o1 = iv1; }
        imv[(size_t)i * 2048 + h * 128 + lane] = o0;
        imv[(size_t)i * 2048 + h * 128 + lane + 64] = o1;
    }
}

__global__ void ln_out(const float* __restrict__ ss, const float* __restrict__ st,
                       const float* __restrict__ g, const float* __restrict__ b,
                       float* __restrict__ out) {
    int idx = blockIdx.x * 256 + threadIdx.x;
    if (idx >= 17 * 2048) return;
    int i = idx >> 11, m = idx & 2047;
    float mean = st[2 * i] * (1.f / 2048.f);
    float var = st[2 * i + 1] * (1.f / 2048.f) - mean * mean;
    float rstd = rsqrtf(var + 1e-5f);
    out[idx] = (ss[idx] - mean) * rstd * g[m] + b[m];
}

extern "C" void kernel_launch(void* const* d_in, const int* in_sizes, int n_in,
                              void* d_out, int out_size, void* d_ws, size_t ws_size,
                              hipStream_t stream) {
    const float* x      = (const float*)d_in[0];
    const float* weight = (const float*)d_in[1];
    const float* bias   = (const float*)d_in[2];
    const float* cls    = (const float*)d_in[3];
    const float* Wqkv   = (const float*)d_in[4];
    const float* Wo     = (const float*)d_in[5];
    const float* ln1_g  = (const float*)d_in[6];
    const float* ln1_b  = (const float*)d_in[7];
    const float* ln2_g  = (const float*)d_in[8];
    const float* ln2_b  = (const float*)d_in[9];
    const float* ln3_g  = (const float*)d_in[10];
    const float* ln3_b  = (const float*)d_in[11];
    const float* fc1_w  = (const float*)d_in[12];
    const float* fc1_b  = (const float*)d_in[13];
    const float* fc2_w  = (const float*)d_in[14];
    const float* fc2_b  = (const float*)d_in[15];
    float* out = (float*)d_out;

    float* ws   = (float*)d_ws;
    float* ss   = ws;                 // 34816
    float* altx = ws + 34816;         // 32768
    float* qkv  = ws + 67584;         // 104448
    float* imv  = ws + 172032;        // 34816
    float* tbuf = ws + 206848;        // 139264
    float* st0  = ws + 346112;        // 34
    float* st1  = ws + 346146;        // 34
    float* P    = ws + 346368;        // up to 3342336 (qkv partials)

    k0_init<<<136, 256, 0, stream>>>(x, bias, cls, ss, altx, st0);
    // ss[1:17] += altx @ weight.T  (S=64, KT=1)
    gemm2<16, 0, 1><<<dim3(8, 64), 256, 0, stream>>>(
        weight, altx, nullptr, nullptr, nullptr, P, nullptr, 2048, 2048);
    red_addss<<<128, 256, 0, stream>>>(P, nullptr, ss + 2048, st0 + 2, 64, 32768);

    for (int k = 0; k < 4; ++k) {
        // qkv = Wqkv[k] @ ln1(ss)  (S=32, KT=2)
        gemm2<17, 1, 2><<<dim3(24, 32), 256, 0, stream>>>(
            Wqkv + (size_t)k * 12582912, ss, st0, ln1_g, ln1_b, P, nullptr,
            6144, 2048);
        red_plain<<<408, 256, 0, stream>>>(P, qkv, 32, 104448);
        attn_kernel<<<16, 64, 0, stream>>>(qkv, imv, st1);
        // ss += imv @ Wo[k].T  (S=64, KT=1); stats -> st1
        gemm2<17, 0, 1><<<dim3(8, 64), 256, 0, stream>>>(
            Wo + (size_t)k * 4194304, imv, nullptr, nullptr, nullptr, P, nullptr,
            2048, 2048);
        red_addss<<<136, 256, 0, stream>>>(P, nullptr, ss, st1, 64, 34816);
        // t = gelu(fc1_w @ ln2(ss) + fc1_b)  (S=16, KT=4); zeroes st0
        gemm2<17, 1, 4><<<dim3(32, 16), 256, 0, stream>>>(
            fc1_w, ss, st1, ln2_g, ln2_b, P, st0, 8192, 2048);
        red_gelu<<<544, 256, 0, stream>>>(P, fc1_b, tbuf, 16, 139264, 8191);
        // ss += fc2_w @ t + fc2_b  (S=64, KT=4); stats -> st0
        gemm2<17, 0, 4><<<dim3(8, 64), 256, 0, stream>>>(
            fc2_w, tbuf, nullptr, nullptr, nullptr, P, nullptr, 2048, 8192);
        red_addss<<<136, 256, 0, stream>>>(P, fc2_b, ss, st0, 64, 34816);
    }
    ln_out<<<136, 256, 0, stream>>>(ss, st0, ln3_g, ln3_b, out);
}

// Round 4
// 773.975 us; speedup vs baseline: 2.0227x; 2.0227x over previous
//
#include <hip/hip_runtime.h>
#include <math.h>

// M=2048, AVGF=16 (17 rows), HA=16 heads, DH=128, TK=4 blocks.
// GEMM: out[i,l] = sum_m act'[i,m] * W[l,m].
// Each wave owns 4 consecutive W rows, streams them sequentially (1KB bursts),
// k-reduces in-wave via shfl butterfly. S-way k-split -> S partial planes
// P[s][i][l], summed by fused reduce kernels. No global atomics except LN stats.

__global__ void k0_init(const float* __restrict__ x,
                        const float* __restrict__ bias,
                        const float* __restrict__ cls,
                        float* __restrict__ ss,
                        float* __restrict__ altx,
                        float* __restrict__ st01) {
    int idx = blockIdx.x * 256 + threadIdx.x;
    if (idx < 17 * 2048) {
        int r = idx >> 11, m = idx & 2047;
        float v = bias[idx];
        if (r == 0) v += cls[m];
        ss[idx] = v;
    }
    if (idx < 16 * 2048) {
        int i = idx >> 11, m = idx & 2047;
        int c1 = m >> 6, c2 = m & 63;
        const float* p = x + (size_t)(c2 * 32 + c1) * 160 + i * 10;
        float s = 0.f;
#pragma unroll
        for (int j = 0; j < 10; ++j) s += p[j];
        altx[idx] = s * 0.1f;
    }
    if (blockIdx.x == 0) {
        int t = threadIdx.x;
        if (t < 68) st01[t] = 0.f;
        __syncthreads();
        float s = 0.f, q = 0.f;
        for (int j = t; j < 2048; j += 256) {
            float v = bias[j] + cls[j];
            s += v; q += v * v;
        }
#pragma unroll
        for (int off = 32; off; off >>= 1) {
            s += __shfl_xor(s, off);
            q += __shfl_xor(q, off);
        }
        __shared__ float ls[4], lq[4];
        int w = t >> 6;
        if ((t & 63) == 0) { ls[w] = s; lq[w] = q; }
        __syncthreads();
        if (t == 0) {
            st01[0] = ls[0] + ls[1] + ls[2] + ls[3];
            st01[1] = lq[0] + lq[1] + lq[2] + lq[3];
        }
    }
}

// MODE 0: act' = act ; MODE 1: act' = LN(act) from raw (sum,sumsq) in st
// MODE 2: act' = gelu(act + g)
// grid (L/16, S); block 256 = 4 waves; wave w owns rows l0+4w..l0+4w+3.
// slab = K/S per block, staged in 1024-col rounds into LDS.
template <int NR, int MODE>
__global__ __launch_bounds__(256) void gemmW(
    const float* __restrict__ W, const float* __restrict__ act,
    const float* __restrict__ st, const float* __restrict__ g,
    const float* __restrict__ b, float* __restrict__ P,
    int L, int K) {
    __shared__ float abuf[NR][1024];
    const int tid = threadIdx.x;
    const int lane = tid & 63;
    const int wv = tid >> 6;
    const int l0 = blockIdx.x * 16;
    const int slab = K / gridDim.y;          // 1024 / 2048 / 4096
    const int k0 = blockIdx.y * slab;
    const int rounds = slab >> 10;

    float acc[NR][4];
#pragma unroll
    for (int i = 0; i < NR; ++i)
#pragma unroll
        for (int r = 0; r < 4; ++r) acc[i][r] = 0.f;

    const float* Wp[4];
#pragma unroll
    for (int r = 0; r < 4; ++r)
        Wp[r] = W + (size_t)(l0 + wv * 4 + r) * K + k0;

    for (int rd = 0; rd < rounds; ++rd) {
        const int ko = k0 + rd * 1024;
        // ---- stage act' round [NR][1024] (coalesced float4) ----
#pragma unroll
        for (int s = 0; s < (NR + 3) / 4; ++s) {
            int i = (tid >> 6) + 4 * s;
            if (i < NR) {
                float mean = 0.f, rstd = 0.f;
                if (MODE == 1) {
                    mean = st[2 * i] * (1.f / 2048.f);
                    float var = st[2 * i + 1] * (1.f / 2048.f) - mean * mean;
                    rstd = rsqrtf(var + 1e-5f);
                }
#pragma unroll
                for (int c = 0; c < 4; ++c) {
                    int fi = c * 64 + (tid & 63);          // float4 col in round
                    int m = ko + fi * 4;
                    float4 v4 = *reinterpret_cast<const float4*>(
                        act + (size_t)i * K + m);
                    if (MODE == 1) {
                        float4 g4 = *reinterpret_cast<const float4*>(g + m);
                        float4 b4 = *reinterpret_cast<const float4*>(b + m);
                        v4.x = (v4.x - mean) * rstd * g4.x + b4.x;
                        v4.y = (v4.y - mean) * rstd * g4.y + b4.y;
                        v4.z = (v4.z - mean) * rstd * g4.z + b4.z;
                        v4.w = (v4.w - mean) * rstd * g4.w + b4.w;
                    } else if (MODE == 2) {
                        float4 g4 = *reinterpret_cast<const float4*>(g + m);
                        v4.x += g4.x; v4.y += g4.y; v4.z += g4.z; v4.w += g4.w;
                        v4.x = 0.5f * v4.x * (1.f + erff(v4.x * 0.70710678f));
                        v4.y = 0.5f * v4.y * (1.f + erff(v4.y * 0.70710678f));
                        v4.z = 0.5f * v4.z * (1.f + erff(v4.z * 0.70710678f));
                        v4.w = 0.5f * v4.w * (1.f + erff(v4.w * 0.70710678f));
                    }
                    *reinterpret_cast<float4*>(&abuf[i][fi * 4]) = v4;
                }
            }
        }
        __syncthreads();
        // ---- compute: 4 chunk-groups of 256 cols ----
#pragma unroll
        for (int cg = 0; cg < 4; ++cg) {
            const int off = rd * 1024 + cg * 256 + lane * 4;  // rel. to k0
            float4 w4[4];
#pragma unroll
            for (int r = 0; r < 4; ++r)
                w4[r] = *reinterpret_cast<const float4*>(Wp[r] + off);
#pragma unroll
            for (int i = 0; i < NR; ++i) {
                const float4 a4 = *reinterpret_cast<const float4*>(
                    &abuf[i][cg * 256 + lane * 4]);
#pragma unroll
                for (int r = 0; r < 4; ++r)
                    acc[i][r] += a4.x * w4[r].x + a4.y * w4[r].y +
                                 a4.z * w4[r].z + a4.w * w4[r].w;
            }
        }
        __syncthreads();
    }
    // ---- epilogue: in-wave butterfly reduce, one output per lane ----
    float vout = 0.f, vout2 = 0.f;
#pragma unroll
    for (int i = 0; i < NR; ++i)
#pragma unroll
        for (int r = 0; r < 4; ++r) {
            float v = acc[i][r];
#pragma unroll
            for (int off = 32; off; off >>= 1) v += __shfl_xor(v, off);
            if (i < 16) { if (lane == i * 4 + r) vout = v; }
            else        { if (lane == r)         vout2 = v; }
        }
    size_t pb = (size_t)blockIdx.y * NR * L + l0 + wv * 4;
    P[pb + (size_t)(lane >> 2) * L + (lane & 3)] = vout;
    if (NR > 16 && lane < 4) P[pb + (size_t)16 * L + lane] = vout2;
}

// ss[idx] += P0+P1 (+fb); accumulate (sum,sumsq) per row into st (pre-zeroed)
__global__ void red_addss(const float* __restrict__ P, const float* __restrict__ fb,
                          float* __restrict__ ss, float* __restrict__ st,
                          int NRL) {
    int idx = blockIdx.x * 256 + threadIdx.x;
    if (idx >= NRL) return;
    float s = P[idx] + P[NRL + idx];
    if (fb != nullptr) s += fb[idx & 2047];
    float v = ss[idx] + s;
    ss[idx] = v;
    float sv = v, q = v * v;
#pragma unroll
    for (int off = 32; off; off >>= 1) {
        sv += __shfl_xor(sv, off);
        q += __shfl_xor(q, off);
    }
    if ((threadIdx.x & 63) == 0) {
        int i = idx >> 11;
        atomicAdd(&st[2 * i], sv);
        atomicAdd(&st[2 * i + 1], q);
    }
}

// one block per head; 64 threads; also zeroes st0/st1 for this iteration
__global__ void attn_kernel(const float* __restrict__ qkv, float* __restrict__ imv,
                            float* __restrict__ st0, float* __restrict__ st1) {
    int h = blockIdx.x, lane = threadIdx.x;
    if (h == 0 && lane < 34) { st0[lane] = 0.f; st1[lane] = 0.f; }
    const float scale = 0.08838834764831845f;  // 1/sqrt(128)
    float run0 = 0.f, run1 = 0.f;
    for (int i = 0; i < 17; ++i) {
        const float* base = qkv + (size_t)i * 6144 + h * 128;
        float q0 = base[lane], q1 = base[lane + 64];
        float k0 = base[2048 + lane], k1 = base[2048 + lane + 64];
        float v0 = base[4096 + lane], v1 = base[4096 + lane + 64];
        float p = q0 * k0 + q1 * k1;
#pragma unroll
        for (int off = 32; off; off >>= 1) p += __shfl_xor(p, off);
        float rsa = p * scale;
        float iv0 = rsa * v0, iv1 = rsa * v1;
        float o0, o1;
        if (i < 16) { run0 += iv0; run1 += iv1; o0 = run0; o1 = run1; }
        else        { o0 = iv0; o1 = iv1; }
        imv[(size_t)i * 2048 + h * 128 + lane] = o0;
        imv[(size_t)i * 2048 + h * 128 + lane + 64] = o1;
    }
}

__global__ void ln_out(const float* __restrict__ ss, const float* __restrict__ st,
                       const float* __restrict__ g, const float* __restrict__ b,
                       float* __restrict__ out) {
    int idx = blockIdx.x * 256 + threadIdx.x;
    if (idx >= 17 * 2048) return;
    int i = idx >> 11, m = idx & 2047;
    float mean = st[2 * i] * (1.f / 2048.f);
    float var = st[2 * i + 1] * (1.f / 2048.f) - mean * mean;
    float rstd = rsqrtf(var + 1e-5f);
    out[idx] = (ss[idx] - mean) * rstd * g[m] + b[m];
}

extern "C" void kernel_launch(void* const* d_in, const int* in_sizes, int n_in,
                              void* d_out, int out_size, void* d_ws, size_t ws_size,
                              hipStream_t stream) {
    const float* x      = (const float*)d_in[0];
    const float* weight = (const float*)d_in[1];
    const float* bias   = (const float*)d_in[2];
    const float* cls    = (const float*)d_in[3];
    const float* Wqkv   = (const float*)d_in[4];
    const float* Wo     = (const float*)d_in[5];
    const float* ln1_g  = (const float*)d_in[6];
    const float* ln1_b  = (const float*)d_in[7];
    const float* ln2_g  = (const float*)d_in[8];
    const float* ln2_b  = (const float*)d_in[9];
    const float* ln3_g  = (const float*)d_in[10];
    const float* ln3_b  = (const float*)d_in[11];
    const float* fc1_w  = (const float*)d_in[12];
    const float* fc1_b  = (const float*)d_in[13];
    const float* fc2_w  = (const float*)d_in[14];
    const float* fc2_b  = (const float*)d_in[15];
    float* out = (float*)d_out;

    float* ws   = (float*)d_ws;
    float* ss   = ws;                 // 34816
    float* altx = ws + 34816;         // 32768
    float* qkv  = ws + 67584;         // 104448
    float* imv  = ws + 172032;        // 34816
    float* tbuf = ws + 206848;        // 139264 (raw fc1 out)
    float* st0  = ws + 346112;        // 34
    float* st1  = ws + 346146;        // 34
    float* P    = ws + 346368;        // 2*17*2048 partials

    k0_init<<<136, 256, 0, stream>>>(x, bias, cls, ss, altx, st0);
    // ss[1:17] += altx @ weight.T   (S=2)
    gemmW<16, 0><<<dim3(128, 2), 256, 0, stream>>>(
        weight, altx, nullptr, nullptr, nullptr, P, 2048, 2048);
    red_addss<<<128, 256, 0, stream>>>(P, nullptr, ss + 2048, st0 + 2, 32768);

    for (int k = 0; k < 4; ++k) {
        // qkv = Wqkv[k] @ ln1(ss)   (S=1, direct)
        gemmW<17, 1><<<dim3(384, 1), 256, 0, stream>>>(
            Wqkv + (size_t)k * 12582912, ss, st0, ln1_g, ln1_b, qkv, 6144, 2048);
        attn_kernel<<<16, 64, 0, stream>>>(qkv, imv, st0, st1);
        // ss += imv @ Wo[k].T       (S=2)
        gemmW<17, 0><<<dim3(128, 2), 256, 0, stream>>>(
            Wo + (size_t)k * 4194304, imv, nullptr, nullptr, nullptr, P, 2048, 2048);
        red_addss<<<136, 256, 0, stream>>>(P, nullptr, ss, st1, 34816);
        // tbuf = fc1_w @ ln2(ss)    (S=1, raw; bias+gelu fused into fc2 stage)
        gemmW<17, 1><<<dim3(512, 1), 256, 0, stream>>>(
            fc1_w, ss, st1, ln2_g, ln2_b, tbuf, 8192, 2048);
        // ss += fc2_w @ gelu(tbuf + fc1_b) + fc2_b   (S=2)
        gemmW<17, 2><<<dim3(128, 2), 256, 0, stream>>>(
            fc2_w, tbuf, nullptr, fc1_b, nullptr, P, 2048, 8192);
        red_addss<<<136, 256, 0, stream>>>(P, fc2_b, ss, st0, 34816);
    }
    ln_out<<<136, 256, 0, stream>>>(ss, st0, ln3_g, ln3_b, out);
}

// Round 5
// 580.673 us; speedup vs baseline: 2.6961x; 1.3329x over previous
//
#include <hip/hip_runtime.h>
#include <math.h>

// M=2048, AVGF=16 (17 rows), HA=16 heads, DH=128, TK=4 blocks.
// GEMM out[i,l] = sum_m act'[i,m] * W[l,m], barrier-free:
// each wave owns 4 consecutive W rows, streams them sequentially (float4),
// act' read straight from L1/L2 (no LDS), in-wave shfl butterfly k-reduce,
// S-way k-split planes P[s][i][l] summed by fused reduce kernels.
// LN/gelu transforms live in the reduce kernels, not the GEMM.

__global__ void k0_init(const float* __restrict__ x,
                        const float* __restrict__ bias,
                        const float* __restrict__ cls,
                        float* __restrict__ ss,
                        float* __restrict__ altx) {
    int idx = blockIdx.x * 256 + threadIdx.x;
    if (idx < 17 * 2048) {
        int r = idx >> 11, m = idx & 2047;
        float v = bias[idx];
        if (r == 0) v += cls[m];
        ss[idx] = v;
    }
    if (idx < 16 * 2048) {
        int i = idx >> 11, m = idx & 2047;
        int c1 = m >> 6, c2 = m & 63;
        const float* p = x + (size_t)(c2 * 32 + c1) * 160 + i * 10;
        float s = 0.f;
#pragma unroll
        for (int j = 0; j < 10; ++j) s += p[j];
        altx[idx] = s * 0.1f;
    }
}

// grid (L/16, S); block 256 = 4 waves; wave owns rows l0..l0+3.
// slab = K/S; lane j covers cols k0 + kk + 4j..4j+3 per 256-col chunk.
template <int NR>
__global__ __launch_bounds__(256) void gemmS(
    const float* __restrict__ W, const float* __restrict__ act,
    float* __restrict__ P, int L, int K) {
    const int lane = threadIdx.x & 63;
    const int wv = threadIdx.x >> 6;
    const int l0 = blockIdx.x * 16 + wv * 4;
    const int slab = K / gridDim.y;
    const int k0 = blockIdx.y * slab;

    float acc[NR][4];
#pragma unroll
    for (int i = 0; i < NR; ++i)
#pragma unroll
        for (int r = 0; r < 4; ++r) acc[i][r] = 0.f;

    const float* Wp = W + (size_t)l0 * K + k0;
    const float* Ap = act + k0;

    for (int kk = 0; kk < slab; kk += 256) {
        const int idx = kk + lane * 4;
        const float4 w40 = *reinterpret_cast<const float4*>(Wp + idx);
        const float4 w41 = *reinterpret_cast<const float4*>(Wp + (size_t)K + idx);
        const float4 w42 = *reinterpret_cast<const float4*>(Wp + (size_t)2 * K + idx);
        const float4 w43 = *reinterpret_cast<const float4*>(Wp + (size_t)3 * K + idx);
#pragma unroll
        for (int i = 0; i < NR; ++i) {
            const float4 a4 = *reinterpret_cast<const float4*>(Ap + (size_t)i * K + idx);
            acc[i][0] += a4.x * w40.x + a4.y * w40.y + a4.z * w40.z + a4.w * w40.w;
            acc[i][1] += a4.x * w41.x + a4.y * w41.y + a4.z * w41.z + a4.w * w41.w;
            acc[i][2] += a4.x * w42.x + a4.y * w42.y + a4.z * w42.z + a4.w * w42.w;
            acc[i][3] += a4.x * w43.x + a4.y * w43.y + a4.z * w43.z + a4.w * w43.w;
        }
    }
    // in-wave butterfly reduce; one output per lane (68 outputs, 64 lanes)
    float vout = 0.f, vout2 = 0.f;
#pragma unroll
    for (int i = 0; i < NR; ++i)
#pragma unroll
        for (int r = 0; r < 4; ++r) {
            float v = acc[i][r];
#pragma unroll
            for (int off = 32; off; off >>= 1) v += __shfl_xor(v, off);
            if (i < 16) { if (lane == i * 4 + r) vout = v; }
            else        { if (lane == r)         vout2 = v; }
        }
    size_t pb = (size_t)blockIdx.y * NR * L + l0;
    P[pb + (size_t)(lane >> 2) * L + (lane & 3)] = vout;
    if (NR > 16 && lane < 4) P[pb + (size_t)16 * L + lane] = vout2;
}

// sum S planes -> out (qkv)
__global__ void red_plain(const float* __restrict__ P, float* __restrict__ out,
                          int S, int NRL) {
    int idx = blockIdx.x * 256 + threadIdx.x;
    float s = 0.f;
    for (int y = 0; y < S; ++y) s += P[(size_t)y * NRL + idx];
    out[idx] = s;
}

// tbuf = gelu(sum S planes + fc1_b)
__global__ void red_gelu(const float* __restrict__ P, const float* __restrict__ fb,
                         float* __restrict__ out, int S, int NRL) {
    int idx = blockIdx.x * 256 + threadIdx.x;
    float s = fb[idx & 8191];
    for (int y = 0; y < S; ++y) s += P[(size_t)y * NRL + idx];
    out[idx] = 0.5f * s * (1.f + erff(s * 0.70710678f));
}

// one block per row: ss[row] += sum_S P[row] (+fb); stats; lnout = LN(ss)*g+b
__global__ void redln(const float* __restrict__ P, int S, int rowoff, int NRL,
                      const float* __restrict__ fb, float* __restrict__ ss,
                      const float* __restrict__ g, const float* __restrict__ b,
                      float* __restrict__ lnout) {
    const int row = blockIdx.x;
    const int tid = threadIdx.x;
    const int base = row * 2048;
    float vv[8];
    float s = 0.f, q = 0.f;
#pragma unroll
    for (int c = 0; c < 8; ++c) {
        int col = tid + c * 256;
        float xv = ss[base + col];
        if (row >= rowoff) {
            const float* pp = P + (size_t)(row - rowoff) * 2048 + col;
            for (int y = 0; y < S; ++y) xv += pp[(size_t)y * NRL];
        }
        if (fb != nullptr) xv += fb[col];
        ss[base + col] = xv;
        vv[c] = xv;
        s += xv;
        q += xv * xv;
    }
#pragma unroll
    for (int off = 32; off; off >>= 1) {
        s += __shfl_xor(s, off);
        q += __shfl_xor(q, off);
    }
    __shared__ float red[8];
    int wv = tid >> 6;
    if ((tid & 63) == 0) { red[wv] = s; red[4 + wv] = q; }
    __syncthreads();
    s = red[0] + red[1] + red[2] + red[3];
    q = red[4] + red[5] + red[6] + red[7];
    float mean = s * (1.f / 2048.f);
    float var = q * (1.f / 2048.f) - mean * mean;
    float rstd = rsqrtf(var + 1e-5f);
#pragma unroll
    for (int c = 0; c < 8; ++c) {
        int col = tid + c * 256;
        lnout[base + col] = (vv[c] - mean) * rstd * g[col] + b[col];
    }
}

// one block per head; 64 threads
__global__ void attn_kernel(const float* __restrict__ qkv, float* __restrict__ imv) {
    int h = blockIdx.x, lane = threadIdx.x;
    const float scale = 0.08838834764831845f;  // 1/sqrt(128)
    float run0 = 0.f, run1 = 0.f;
    for (int i = 0; i < 17; ++i) {
        const float* base = qkv + (size_t)i * 6144 + h * 128;
        float q0 = base[lane], q1 = base[lane + 64];
        float k0 = base[2048 + lane], k1 = base[2048 + lane + 64];
        float v0 = base[4096 + lane], v1 = base[4096 + lane + 64];
        float p = q0 * k0 + q1 * k1;
#pragma unroll
        for (int off = 32; off; off >>= 1) p += __shfl_xor(p, off);
        float rsa = p * scale;
        float iv0 = rsa * v0, iv1 = rsa * v1;
        float o0, o1;
        if (i < 16) { run0 += iv0; run1 += iv1; o0 = run0; o1 = run1; }
        else        { o0 = iv0; o1 = iv1; }
        imv[(size_t)i * 2048 + h * 128 + lane] = o0;
        imv[(size_t)i * 2048 + h * 128 + lane + 64] = o1;
    }
}

extern "C" void kernel_launch(void* const* d_in, const int* in_sizes, int n_in,
                              void* d_out, int out_size, void* d_ws, size_t ws_size,
                              hipStream_t stream) {
    const float* x      = (const float*)d_in[0];
    const float* weight = (const float*)d_in[1];
    const float* bias   = (const float*)d_in[2];
    const float* cls    = (const float*)d_in[3];
    const float* Wqkv   = (const float*)d_in[4];
    const float* Wo     = (const float*)d_in[5];
    const float* ln1_g  = (const float*)d_in[6];
    const float* ln1_b  = (const float*)d_in[7];
    const float* ln2_g  = (const float*)d_in[8];
    const float* ln2_b  = (const float*)d_in[9];
    const float* ln3_g  = (const float*)d_in[10];
    const float* ln3_b  = (const float*)d_in[11];
    const float* fc1_w  = (const float*)d_in[12];
    const float* fc1_b  = (const float*)d_in[13];
    const float* fc2_w  = (const float*)d_in[14];
    const float* fc2_b  = (const float*)d_in[15];
    float* out = (float*)d_out;

    float* ws     = (float*)d_ws;
    float* ss     = ws;                  // 34816
    float* altx   = ws + 34816;          // 32768
    float* qkv    = ws + 67584;          // 104448
    float* imv    = ws + 172032;         // 34816
    float* tbuf   = ws + 206848;         // 139264
    float* ln1buf = ws + 346112;         // 34816
    float* ln2buf = ws + 380928;         // 34816
    float* P      = ws + 415744;         // up to 278528

    k0_init<<<136, 256, 0, stream>>>(x, bias, cls, ss, altx);
    // ss[1:17] += altx @ weight.T  (S=4, slab 512); then ln1buf = LN1(ss)
    gemmS<16><<<dim3(128, 4), 256, 0, stream>>>(weight, altx, P, 2048, 2048);
    redln<<<17, 256, 0, stream>>>(P, 4, 1, 32768, nullptr, ss, ln1_g, ln1_b, ln1buf);

    for (int k = 0; k < 4; ++k) {
        // qkv = Wqkv[k] @ ln1(ss)   (S=2, slab 1024)
        gemmS<17><<<dim3(384, 2), 256, 0, stream>>>(
            Wqkv + (size_t)k * 12582912, ln1buf, P, 6144, 2048);
        red_plain<<<408, 256, 0, stream>>>(P, qkv, 2, 104448);
        attn_kernel<<<16, 64, 0, stream>>>(qkv, imv);
        // ss += imv @ Wo[k].T       (S=4, slab 512); ln2buf = LN2(ss)
        gemmS<17><<<dim3(128, 4), 256, 0, stream>>>(
            Wo + (size_t)k * 4194304, imv, P, 2048, 2048);
        redln<<<17, 256, 0, stream>>>(P, 4, 0, 34816, nullptr, ss, ln2_g, ln2_b, ln2buf);
        // fc1 raw (S=2, slab 1024); tbuf = gelu(sum + fc1_b)
        gemmS<17><<<dim3(512, 2), 256, 0, stream>>>(fc1_w, ln2buf, P, 8192, 2048);
        red_gelu<<<544, 256, 0, stream>>>(P, fc1_b, tbuf, 2, 139264);
        // ss += fc2_w @ tbuf + fc2_b (S=8, slab 1024); ln -> next ln1buf / out
        gemmS<17><<<dim3(128, 8), 256, 0, stream>>>(fc2_w, tbuf, P, 2048, 8192);
        if (k < 3)
            redln<<<17, 256, 0, stream>>>(P, 8, 0, 34816, fc2_b, ss, ln1_g, ln1_b, ln1buf);
        else
            redln<<<17, 256, 0, stream>>>(P, 8, 0, 34816, fc2_b, ss, ln3_g, ln3_b, out);
    }
}